// Round 6
// baseline (193.595 us; speedup 1.0000x reference)
//
#include <hip/hip_runtime.h>

#define HIDDEN 128
#define SLOT_H 264
#define BSHIFT 10          // dst bucket = dst >> 10
#define NBMAX 128          // >= (100000>>10)+1 = 98

typedef _Float16 f16;
typedef f16 f16x2 __attribute__((ext_vector_type(2)));
typedef f16 f16x8 __attribute__((ext_vector_type(8)));
typedef float f32x16 __attribute__((ext_vector_type(16)));
typedef unsigned long long ull;

static __device__ __forceinline__ float fdot2(f16x2 a, f16x2 b, float c) {
    return __builtin_amdgcn_fdot2(a, b, c, false);   // v_dot2_f32_f16
}

// wsh_t[n][k] = Wsym[k][n]; also zeros hist/cursor (ws is poisoned each call)
__global__ __launch_bounds__(256) void prep_w(const float* __restrict__ w,
                                              f16* __restrict__ wsh_t,
                                              int* __restrict__ hist) {
    int idx = blockIdx.x * 256 + threadIdx.x;   // 0..16383
    if (idx < 2 * NBMAX) hist[idx] = 0;         // hist + cursor
    int n = idx >> 7, k = idx & 127;
    wsh_t[idx] = (f16)(w[k * HIDDEN + n] + w[n * HIDDEN + k]);
}

// histogram of dst buckets
__global__ __launch_bounds__(256) void hist_k(const int* __restrict__ eidx,
                                              int* __restrict__ hist, int E, int nb) {
    __shared__ int h[NBMAX];
    int tid = threadIdx.x;
    if (tid < NBMAX) h[tid] = 0;
    __syncthreads();
    for (int e = blockIdx.x * 256 + tid; e < E; e += gridDim.x * 256)
        atomicAdd(&h[eidx[E + e] >> BSHIFT], 1);
    __syncthreads();
    if (tid < nb && h[tid]) atomicAdd(&hist[tid], h[tid]);
}

// exclusive prefix -> cursor
__global__ void scan_k(const int* __restrict__ hist, int* __restrict__ cursor, int nb) {
    if (threadIdx.x == 0) {
        int s = 0;
        for (int i = 0; i < nb; ++i) { cursor[i] = s; s += hist[i]; }
    }
}

// block-aggregated counting scatter: perm[pos] = src | dst<<17 | e<<34
__global__ __launch_bounds__(256) void scatter_k(const int* __restrict__ eidx,
                                                 int* __restrict__ cursor,
                                                 ull* __restrict__ perm, int E, int nb) {
    __shared__ int lh[NBMAX], lbase[NBMAX], lrank[NBMAX];
    int tid = threadIdx.x;
    int base = blockIdx.x * 4096;
    if (tid < NBMAX) { lh[tid] = 0; lrank[tid] = 0; }
    __syncthreads();
    int s[16], d[16], bb[16];
    #pragma unroll
    for (int i = 0; i < 16; ++i) {
        int e = base + i * 256 + tid;
        bb[i] = -1;
        if (e < E) {
            s[i] = eidx[e]; d[i] = eidx[E + e];
            bb[i] = d[i] >> BSHIFT;
            atomicAdd(&lh[bb[i]], 1);
        }
    }
    __syncthreads();
    if (tid < nb && lh[tid]) lbase[tid] = atomicAdd(&cursor[tid], lh[tid]);
    __syncthreads();
    #pragma unroll
    for (int i = 0; i < 16; ++i) {
        if (bb[i] >= 0) {
            int e = base + i * 256 + tid;
            int r = atomicAdd(&lrank[bb[i]], 1);
            perm[lbase[bb[i]] + r] =
                (ull)s[i] | ((ull)d[i] << 17) | ((ull)e << 34);
        }
    }
}

// uh = (f16)(z @ Wsym), zh = (f16)z — fused MFMA 32x32x16_f16 (R5, measured OK)
__global__ __launch_bounds__(256, 3) void gemm_mfma2(const float* __restrict__ z,
                                                     const f16* __restrict__ wsh_t,
                                                     f16* __restrict__ zh,
                                                     f16* __restrict__ uh, int nrows) {
    __shared__ f16 afrag[64 * SLOT_H];
    int tid = threadIdx.x;
    int row0 = blockIdx.x * 128;
    if (row0 > nrows - 128) row0 = nrows - 128;

    {
        const float4* zg = (const float4*)(z + (size_t)row0 * HIDDEN);
        f16x8* zhg = (f16x8*)(zh + (size_t)row0 * HIDDEN);
        #pragma unroll
        for (int it = 0; it < 8; ++it) {
            int g = it * 256 + tid;
            float4 v0 = zg[2 * g];
            float4 v1 = zg[2 * g + 1];
            f16x8 h = {(f16)v0.x, (f16)v0.y, (f16)v0.z, (f16)v0.w,
                       (f16)v1.x, (f16)v1.y, (f16)v1.z, (f16)v1.w};
            zhg[g] = h;
            int row = g >> 4, ch = g & 15;
            int slot = (row >> 5) * 16 + ch;
            *(f16x8*)&afrag[slot * SLOT_H + (row & 31) * 8] = h;
        }
    }
    __syncthreads();

    int wave = tid >> 6, lane = tid & 63;
    int m = lane & 31, half = lane >> 5;
    const f16* wb = wsh_t + (size_t)m * HIDDEN + half * 8;

    f32x16 acc0, acc1, acc2, acc3;
    #pragma unroll
    for (int r = 0; r < 16; ++r) { acc0[r] = 0.f; acc1[r] = 0.f; acc2[r] = 0.f; acc3[r] = 0.f; }

    #pragma unroll
    for (int ks = 0; ks < 8; ++ks) {
        f16x8 a = *(const f16x8*)&afrag[(wave * 16 + ks * 2 + half) * SLOT_H + m * 8];
        f16x8 b0 = *(const f16x8*)&wb[ 0 * HIDDEN + 16 * ks];
        f16x8 b1 = *(const f16x8*)&wb[32 * HIDDEN + 16 * ks];
        f16x8 b2 = *(const f16x8*)&wb[64 * HIDDEN + 16 * ks];
        f16x8 b3 = *(const f16x8*)&wb[96 * HIDDEN + 16 * ks];
        acc0 = __builtin_amdgcn_mfma_f32_32x32x16_f16(a, b0, acc0, 0, 0, 0);
        acc1 = __builtin_amdgcn_mfma_f32_32x32x16_f16(a, b1, acc1, 0, 0, 0);
        acc2 = __builtin_amdgcn_mfma_f32_32x32x16_f16(a, b2, acc2, 0, 0, 0);
        acc3 = __builtin_amdgcn_mfma_f32_32x32x16_f16(a, b3, acc3, 0, 0, 0);
    }

    f16* ur = uh + (size_t)(row0 + wave * 32) * HIDDEN;
    #pragma unroll
    for (int r = 0; r < 16; ++r) {
        int row = (r & 3) + 8 * (r >> 2) + 4 * half;
        f16* p = ur + (size_t)row * HIDDEN + m;
        p[0]  = (f16)acc0[r];
        p[32] = (f16)acc1[r];
        p[64] = (f16)acc2[r];
        p[96] = (f16)acc3[r];
    }
}

// binned edge scoring: sorted-by-dst-bucket order + XCD swizzle -> dst gathers L2-hit
__global__ __launch_bounds__(256) void edge_bin(const f16* __restrict__ uh,
                                                const f16* __restrict__ zh,
                                                const ull* __restrict__ perm,
                                                float* __restrict__ out, int E, int cpx) {
    int tid = threadIdx.x;
    int g = tid >> 4, t = tid & 15;
    int b = blockIdx.x;
    int chunk = (b & 7) * cpx + (b >> 3);     // XCD b%8 -> contiguous 1/8 of sorted edges
    int e = chunk * 16 + g;
    if (e >= E) return;
    ull p = perm[e];
    int src = (int)(p & 0x1FFFF);
    int dst = (int)((p >> 17) & 0x1FFFF);
    int eid = (int)(p >> 34);
    const float4* a4 = (const float4*)(uh + (size_t)src * HIDDEN);
    const float4* b4 = (const float4*)(zh + (size_t)dst * HIDDEN);
    float4 av = a4[t], bv = b4[t];
    const f16x2* ap = (const f16x2*)&av;
    const f16x2* bp = (const f16x2*)&bv;
    float s = 0.f;
    #pragma unroll
    for (int i = 0; i < 4; ++i) s = fdot2(ap[i], bp[i], s);
    #pragma unroll
    for (int off = 8; off > 0; off >>= 1) s += __shfl_down(s, off, 16);
    if (t == 0) out[eid] = 1.0f / (1.0f + __expf(-s));
}

// fallback (R5 path) if workspace too small for perm
__global__ __launch_bounds__(256) void edge_score16(const f16* __restrict__ uh,
                                                    const f16* __restrict__ zh,
                                                    const int* __restrict__ eidx,
                                                    float* __restrict__ out, int E) {
    int tid = threadIdx.x;
    int g = tid >> 4, t = tid & 15;
    int e = blockIdx.x * 16 + g;
    if (e >= E) return;
    int src = eidx[e];
    int dst = eidx[E + e];
    const float4* a4 = (const float4*)(uh + (size_t)src * HIDDEN);
    const float4* b4 = (const float4*)(zh + (size_t)dst * HIDDEN);
    float4 av = a4[t], bv = b4[t];
    const f16x2* ap = (const f16x2*)&av;
    const f16x2* bp = (const f16x2*)&bv;
    float s = 0.f;
    #pragma unroll
    for (int i = 0; i < 4; ++i) s = fdot2(ap[i], bp[i], s);
    #pragma unroll
    for (int off = 8; off > 0; off >>= 1) s += __shfl_down(s, off, 16);
    if (t == 0) out[e] = 1.0f / (1.0f + __expf(-s));
}

extern "C" void kernel_launch(void* const* d_in, const int* in_sizes, int n_in,
                              void* d_out, int out_size, void* d_ws, size_t ws_size,
                              hipStream_t stream) {
    const float* z    = (const float*)d_in[0];
    const int*   eidx = (const int*)d_in[1];
    const float* w    = (const float*)d_in[2];
    float* out = (float*)d_out;

    int nrows = in_sizes[0] / HIDDEN;   // 100000
    int E = out_size;                    // 1000000
    int nb = (nrows >> BSHIFT) + 1;      // 98

    f16* wsh_t = (f16*)d_ws;                               // 32 KB
    f16* zh    = wsh_t + HIDDEN * HIDDEN;                  // 25.6 MB
    f16* uh    = zh + (size_t)nrows * HIDDEN;              // 25.6 MB
    int* hist  = (int*)(uh + (size_t)nrows * HIDDEN);      // NBMAX ints
    int* cursor = hist + NBMAX;                            // NBMAX ints
    ull* perm  = (ull*)(cursor + NBMAX);                   // 8 MB

    size_t need = (size_t)((char*)(perm + E) - (char*)d_ws);
    bool binned = ws_size >= need;       // ws_size fixed per session -> same work every call

    prep_w<<<64, 256, 0, stream>>>(w, wsh_t, hist);
    if (binned) {
        hist_k<<<256, 256, 0, stream>>>(eidx, hist, E, nb);
        scan_k<<<1, 64, 0, stream>>>(hist, cursor, nb);
        scatter_k<<<(E + 4095) / 4096, 256, 0, stream>>>(eidx, cursor, perm, E, nb);
    }
    gemm_mfma2<<<(nrows + 127) / 128, 256, 0, stream>>>(z, wsh_t, zh, uh, nrows);
    if (binned) {
        int nch = (E + 15) / 16;
        int cpx = (nch + 7) / 8;
        edge_bin<<<8 * cpx, 256, 0, stream>>>(uh, zh, perm, out, E, cpx);
    } else {
        edge_score16<<<(E + 15) / 16, 256, 0, stream>>>(uh, zh, eidx, out, E);
    }
}